// Round 3
// baseline (482.865 us; speedup 1.0000x reference)
//
#include <hip/hip_runtime.h>
#include <math.h>

#define T_TOK 2048
#define HD 768
#define ID 1536
#define NE 8
#define CAP 768
#define TK 4096

typedef __bf16 bf16_t;
typedef __bf16 bf16x8 __attribute__((ext_vector_type(8)));
typedef __bf16 bf16x4 __attribute__((ext_vector_type(4)));
typedef float floatx4 __attribute__((ext_vector_type(4)));

// ---------------- K1: fused cast + routing (wave per token) ----------------
__global__ void k_route(const float* __restrict__ x, const float* __restrict__ wg,
                        bf16_t* __restrict__ xbf, int2* __restrict__ idx2,
                        float2* __restrict__ wc2, float* __restrict__ imp) {
  int t = blockIdx.x * 4 + (threadIdx.x >> 6);
  int lane = threadIdx.x & 63;
  const float* xr = x + (size_t)t * HD;
  int off = lane * 12;
  float4 a = *(const float4*)(xr + off);
  float4 b = *(const float4*)(xr + off + 4);
  float4 c = *(const float4*)(xr + off + 8);
  float xv[12] = {a.x, a.y, a.z, a.w, b.x, b.y, b.z, b.w, c.x, c.y, c.z, c.w};
  bf16x4 s0, s1, s2;
#pragma unroll
  for (int j = 0; j < 4; ++j) { s0[j] = (bf16_t)xv[j]; s1[j] = (bf16_t)xv[4 + j]; s2[j] = (bf16_t)xv[8 + j]; }
  bf16_t* xo = xbf + (size_t)t * HD + off;
  *(bf16x4*)xo = s0; *(bf16x4*)(xo + 4) = s1; *(bf16x4*)(xo + 8) = s2;

  float acc[8] = {0, 0, 0, 0, 0, 0, 0, 0};
#pragma unroll
  for (int jj = 0; jj < 12; ++jj) {
    const float4* wr = (const float4*)(wg + (size_t)(off + jj) * 8);
    float4 w0 = wr[0], w1 = wr[1];
    float v = xv[jj];
    acc[0] += v * w0.x; acc[1] += v * w0.y; acc[2] += v * w0.z; acc[3] += v * w0.w;
    acc[4] += v * w1.x; acc[5] += v * w1.y; acc[6] += v * w1.z; acc[7] += v * w1.w;
  }
#pragma unroll
  for (int e = 0; e < 8; ++e) {
    float v = acc[e];
    for (int s = 1; s < 64; s <<= 1) v += __shfl_xor(v, s, 64);
    acc[e] = v;
  }
  float mx = acc[0];
#pragma unroll
  for (int e = 1; e < 8; ++e) mx = fmaxf(mx, acc[e]);
  float p[8], sum = 0.f;
#pragma unroll
  for (int e = 0; e < 8; ++e) { p[e] = __expf(acc[e] - mx); sum += p[e]; }
#pragma unroll
  for (int e = 0; e < 8; ++e) p[e] /= sum;
  if (lane < 8) atomicAdd(&imp[lane], p[lane]);
  if (lane == 0) {
    int e0 = 0;
#pragma unroll
    for (int e = 1; e < 8; ++e) if (p[e] > p[e0]) e0 = e;
    int e1 = (e0 == 0) ? 1 : 0;
#pragma unroll
    for (int e = 0; e < 8; ++e) if (e != e0 && p[e] > p[e1]) e1 = e;
    float denom = p[e0] + p[e1] + 1e-8f;
    float w0c = fminf(fmaxf(p[e0] / denom, 1e-8f), 10.f);
    float w1c = fminf(fmaxf(p[e1] / denom, 1e-8f), 10.f);
    idx2[t] = make_int2(e0, e1);
    wc2[t] = make_float2(w0c, w1c);
  }
}

// ---------------- K2: capacity ranks + placement (16 waves) ----------------
__global__ void k_scan(const int2* __restrict__ idx2, const float2* __restrict__ wc2,
                       const float* __restrict__ imp,
                       int* __restrict__ tok_of_row, float* __restrict__ wgt_of_row,
                       int2* __restrict__ cnt_start, float* __restrict__ aux_out) {
  __shared__ int sTot[16];
  __shared__ int sPos[8];
  int tid = threadIdx.x;
  int w = tid >> 6, lane = tid & 63;
  int s = w >> 3, e = w & 7;
  int t0 = lane * 32;
  int cnt = 0;
  for (int j = 0; j < 32; ++j) {
    int2 p = idx2[t0 + j];
    int ex = s ? p.y : p.x;
    cnt += (ex == e) ? 1 : 0;
  }
  int incl = cnt;
  for (int d = 1; d < 64; d <<= 1) {
    int v = __shfl_up(incl, d, 64);
    if (lane >= d) incl += v;
  }
  int excl = incl - cnt;
  if (lane == 63) sTot[w] = incl;
  __syncthreads();
  if (tid == 0) {
    int run = 0;
    float a = 0.f;
    for (int ee = 0; ee < 8; ++ee) {
      int k = min(sTot[ee], CAP) + min(sTot[8 + ee], CAP);
      sPos[ee] = run;
      cnt_start[ee] = make_int2(run, k);
      a += ((float)k / (float)TK) * (imp[ee] / (float)T_TOK);
      run += k;
    }
    a *= (float)NE;
    int dropped = TK - run;
    if (dropped > 0) a += (float)dropped / (float)T_TOK * 0.1f;
    a = fminf(a, 1.f) * 0.001f;
    aux_out[0] = a;
  }
  __syncthreads();
  int rank = excl;
  for (int j = 0; j < 32; ++j) {
    int t = t0 + j;
    int2 p = idx2[t];
    int ex = s ? p.y : p.x;
    if (ex == e) {
      rank++;
      if (rank <= CAP) {
        int pos = atomicAdd(&sPos[e], 1);
        tok_of_row[pos] = t;
        float2 wv = wc2[t];
        wgt_of_row[pos] = s ? wv.y : wv.x;
      }
    }
  }
}

// ---------------- K3: grouped GEMM1, LDS-resident weight panel ----------------
// grid 768: e = bx&7 (XCD pin), cy = bx>>3 in [0,96): 16 I-cols each.
// Stage fp32 w1/w3 panel (16n x 768k) -> bf16 LDS once; then barrier-free
// K-loop: A-frags per-lane direct from xbf, B-frags ds_read_b128.
__global__ __launch_bounds__(256, 3)
void k_gemm1(const bf16_t* __restrict__ xbf, const float* __restrict__ w1,
             const float* __restrict__ w3, const int* __restrict__ tok_of_row,
             const int2* __restrict__ cnt_start, bf16_t* __restrict__ h_ws) {
  int e = blockIdx.x & 7, cy = blockIdx.x >> 3;
  int n0 = cy * 16;
  int2 cs = cnt_start[e];
  int nrows = cs.y;
  if (nrows <= 0) return;
  int grow0 = cs.x;

  // [mat][kc(24)][n(16)][kpos(32)] bf16 = 48 KB; chunk-XOR swizzle within row
  __shared__ __attribute__((aligned(16))) bf16_t BL[2][24 * 512];

  int tid = threadIdx.x;
  {
    int i4 = (tid & 3) * 4;
    int hb = (tid >> 2) * 12;
    const float* s1 = w1 + ((size_t)e * HD + hb) * ID + n0 + i4;
    const float* s3 = w3 + ((size_t)e * HD + hb) * ID + n0 + i4;
    for (int hh = 0; hh < 12; ++hh) {
      int h = hb + hh;
      int kc = h >> 5, kin = h & 31;
      int c8 = kin >> 3, kb = kin & 7;
      float4 v1 = *(const float4*)(s1 + (size_t)hh * ID);
      float4 v3 = *(const float4*)(s3 + (size_t)hh * ID);
      float a1[4] = {v1.x, v1.y, v1.z, v1.w};
      float a3[4] = {v3.x, v3.y, v3.z, v3.w};
#pragma unroll
      for (int c = 0; c < 4; ++c) {
        int n = i4 + c;
        int p = c8 ^ ((n >> 1) & 3);
        int idx = kc * 512 + n * 32 + p * 8 + kb;
        BL[0][idx] = (bf16_t)a1[c];
        BL[1][idx] = (bf16_t)a3[c];
      }
    }
  }
  __syncthreads();

  int lane = tid & 63, w = tid >> 6;
  int lr = lane & 15, q = lane >> 4;
  int boff = lr * 32 + (q ^ ((lr >> 1) & 3)) * 8;

  int njt = (nrows + 255) >> 8;
  for (int j = 0; j < njt; ++j) {
    int rbase = j * 256 + w * 64;
    const bf16_t* ap[4];
#pragma unroll
    for (int mf = 0; mf < 4; ++mf) {
      int tok = tok_of_row[grow0 + min(rbase + mf * 16 + lr, nrows - 1)];
      ap[mf] = xbf + (size_t)tok * HD + q * 8;
    }
    floatx4 accg[4] = {};
    floatx4 accu[4] = {};
    bf16x8 a[2][2][4], b1[2][2], b3[2][2];
#pragma unroll
    for (int cc = 0; cc < 2; ++cc) {
#pragma unroll
      for (int mf = 0; mf < 4; ++mf) a[0][cc][mf] = *(const bf16x8*)(ap[mf] + cc * 32);
      b1[0][cc] = *(const bf16x8*)&BL[0][cc * 512 + boff];
      b3[0][cc] = *(const bf16x8*)&BL[1][cc * 512 + boff];
    }
#pragma unroll
    for (int u = 0; u < 12; ++u) {
      int s = u & 1;
      if (u < 11) {
        int kc0 = (u + 1) * 2;
#pragma unroll
        for (int cc = 0; cc < 2; ++cc) {
#pragma unroll
          for (int mf = 0; mf < 4; ++mf)
            a[s ^ 1][cc][mf] = *(const bf16x8*)(ap[mf] + (size_t)(kc0 + cc) * 32);
          b1[s ^ 1][cc] = *(const bf16x8*)&BL[0][(kc0 + cc) * 512 + boff];
          b3[s ^ 1][cc] = *(const bf16x8*)&BL[1][(kc0 + cc) * 512 + boff];
        }
      }
#pragma unroll
      for (int cc = 0; cc < 2; ++cc)
#pragma unroll
        for (int mf = 0; mf < 4; ++mf) {
          accg[mf] = __builtin_amdgcn_mfma_f32_16x16x32_bf16(a[s][cc][mf], b1[s][cc], accg[mf], 0, 0, 0);
          accu[mf] = __builtin_amdgcn_mfma_f32_16x16x32_bf16(a[s][cc][mf], b3[s][cc], accu[mf], 0, 0, 0);
        }
    }
#pragma unroll
    for (int mf = 0; mf < 4; ++mf)
#pragma unroll
      for (int rr = 0; rr < 4; ++rr) {
        int r = rbase + mf * 16 + q * 4 + rr;
        if (r < nrows) {
          float gg = accg[mf][rr], uu = accu[mf][rr];
          float sg = gg / (1.f + __expf(-gg));
          h_ws[(size_t)(grow0 + r) * ID + n0 + lr] = (bf16_t)(sg * uu);
        }
      }
  }
}

// ---------------- K4: grouped GEMM2, LDS-resident w2 panel + atomic combine ----
// grid 384: e = bx&7, ch = bx>>3 in [0,48): 16 H-cols each.
__global__ __launch_bounds__(256, 3)
void k_gemm2(const bf16_t* __restrict__ h_ws, const float* __restrict__ w2,
             const int* __restrict__ tok_of_row, const float* __restrict__ wgt_of_row,
             const int2* __restrict__ cnt_start, float* __restrict__ out) {
  int e = blockIdx.x & 7, ch = blockIdx.x >> 3;
  int n0 = ch * 16;
  int2 cs = cnt_start[e];
  int nrows = cs.y;
  if (nrows <= 0) return;
  int grow0 = cs.x;

  // [kc(48)][n(16)][kpos(32)] bf16 = 48 KB
  __shared__ __attribute__((aligned(16))) bf16_t BL[48 * 512];

  int tid = threadIdx.x;
  {
    int n4 = (tid & 3) * 4;
    int ib = (tid >> 2) * 24;
    const float* s2 = w2 + ((size_t)e * ID + ib) * HD + n0 + n4;
    for (int ii = 0; ii < 24; ++ii) {
      int i = ib + ii;
      int kc = i >> 5, kin = i & 31;
      int c8 = kin >> 3, kb = kin & 7;
      float4 v = *(const float4*)(s2 + (size_t)ii * HD);
      float av[4] = {v.x, v.y, v.z, v.w};
#pragma unroll
      for (int c = 0; c < 4; ++c) {
        int n = n4 + c;
        int p = c8 ^ ((n >> 1) & 3);
        BL[kc * 512 + n * 32 + p * 8 + kb] = (bf16_t)av[c];
      }
    }
  }
  __syncthreads();

  int lane = tid & 63, w = tid >> 6;
  int lr = lane & 15, q = lane >> 4;
  int boff = lr * 32 + (q ^ ((lr >> 1) & 3)) * 8;

  int njt = (nrows + 255) >> 8;
  for (int j = 0; j < njt; ++j) {
    int rbase = j * 256 + w * 64;
    const bf16_t* ap[4];
#pragma unroll
    for (int mf = 0; mf < 4; ++mf) {
      int row = grow0 + min(rbase + mf * 16 + lr, nrows - 1);
      ap[mf] = h_ws + (size_t)row * ID + q * 8;
    }
    floatx4 acc[4] = {};
    bf16x8 a[2][2][4], bb[2][2];
#pragma unroll
    for (int cc = 0; cc < 2; ++cc) {
#pragma unroll
      for (int mf = 0; mf < 4; ++mf) a[0][cc][mf] = *(const bf16x8*)(ap[mf] + cc * 32);
      bb[0][cc] = *(const bf16x8*)&BL[cc * 512 + boff];
    }
#pragma unroll
    for (int u = 0; u < 24; ++u) {
      int s = u & 1;
      if (u < 23) {
        int kc0 = (u + 1) * 2;
#pragma unroll
        for (int cc = 0; cc < 2; ++cc) {
#pragma unroll
          for (int mf = 0; mf < 4; ++mf)
            a[s ^ 1][cc][mf] = *(const bf16x8*)(ap[mf] + (size_t)(kc0 + cc) * 32);
          bb[s ^ 1][cc] = *(const bf16x8*)&BL[(kc0 + cc) * 512 + boff];
        }
      }
#pragma unroll
      for (int cc = 0; cc < 2; ++cc)
#pragma unroll
        for (int mf = 0; mf < 4; ++mf)
          acc[mf] = __builtin_amdgcn_mfma_f32_16x16x32_bf16(a[s][cc][mf], bb[s][cc], acc[mf], 0, 0, 0);
    }
#pragma unroll
    for (int mf = 0; mf < 4; ++mf)
#pragma unroll
      for (int rr = 0; rr < 4; ++rr) {
        int r = rbase + mf * 16 + q * 4 + rr;
        if (r < nrows) {
          int grow = grow0 + r;
          int tok = tok_of_row[grow];
          float wgt = wgt_of_row[grow];
          atomicAdd(&out[(size_t)tok * HD + n0 + lr], wgt * acc[mf][rr]);
        }
      }
  }
}

extern "C" void kernel_launch(void* const* d_in, const int* in_sizes, int n_in,
                              void* d_out, int out_size, void* d_ws, size_t ws_size,
                              hipStream_t stream) {
  const float* x  = (const float*)d_in[0];
  const float* wg = (const float*)d_in[1];
  const float* w1 = (const float*)d_in[2];
  const float* w3 = (const float*)d_in[3];
  const float* w2 = (const float*)d_in[4];
  float* out = (float*)d_out;

  char* ws = (char*)d_ws;
  bf16_t* xbf  = (bf16_t*)(ws + 0);          //  3,145,728
  bf16_t* h_ws = (bf16_t*)(ws + 3145728);    // 12,582,912
  int2*   idx2 = (int2*)(ws + 15728640);
  float2* wc2  = (float2*)(ws + 15745024);
  int*    tok_of_row = (int*)(ws + 15761408);
  float*  wgt_of_row = (float*)(ws + 15777792);
  int2*   cnt_start  = (int2*)(ws + 15794176);
  float*  imp        = (float*)(ws + 15794240);

  float* aux_out = out + (size_t)T_TOK * HD;

  hipMemsetAsync(out, 0, (size_t)T_TOK * HD * sizeof(float), stream);
  hipMemsetAsync(imp, 0, NE * sizeof(float), stream);
  k_route<<<512, 256, 0, stream>>>(x, wg, xbf, idx2, wc2, imp);
  k_scan<<<1, 1024, 0, stream>>>(idx2, wc2, imp, tok_of_row, wgt_of_row,
                                 cnt_start, aux_out);
  k_gemm1<<<768, 256, 0, stream>>>(xbf, w1, w3, tok_of_row, cnt_start, h_ws);
  k_gemm2<<<384, 256, 0, stream>>>(h_ws, w2, tok_of_row, wgt_of_row,
                                   cnt_start, out);
}

// Round 4
// 277.800 us; speedup vs baseline: 1.7382x; 1.7382x over previous
//
#include <hip/hip_runtime.h>
#include <math.h>

#define T_TOK 2048
#define HD 768
#define ID 1536
#define NE 8
#define CAP 768
#define TK 4096
#define RT 12      // max 128-row tiles per expert (2*CAP/128)
#define NB1 24     // ID/64 col-strips for gemm1
#define KC1 24     // HD/32 K-steps for gemm1
#define NB2 12     // HD/64 col-strips for gemm2
#define KC2 48     // ID/32 K-steps for gemm2

typedef __bf16 bf16_t;
typedef __bf16 bf16x8 __attribute__((ext_vector_type(8)));
typedef __bf16 bf16x4 __attribute__((ext_vector_type(4)));
typedef float floatx4 __attribute__((ext_vector_type(4)));

__device__ __forceinline__ void gld16(const bf16_t* g, bf16_t* l) {
  __builtin_amdgcn_global_load_lds(
      (__attribute__((address_space(1))) void*)(g),
      (__attribute__((address_space(3))) void*)(l),
      16, 0, 0);
}

// ---------------- K1: fused routing + out-zero + weight repack ----------------
// blocks [0,512): routing (4 tokens/block, wave per token) + zero out slice
// blocks [512,992): repack fp32 weights -> pre-swizzled bf16 B-fragment blobs
__global__ void k_prep(const float* __restrict__ x, const float* __restrict__ wg,
                       const float* __restrict__ w1, const float* __restrict__ w3,
                       const float* __restrict__ w2,
                       bf16_t* __restrict__ xbf, bf16_t* __restrict__ w1b,
                       bf16_t* __restrict__ w3b, bf16_t* __restrict__ w2b,
                       int2* __restrict__ idx2, float2* __restrict__ wc2,
                       float* __restrict__ probs8, float* __restrict__ outz) {
  int b = blockIdx.x;
  int tid = threadIdx.x;
  if (b < 512) {
    // zero the output slice (gemm2 accumulates with atomics)
#pragma unroll
    for (int k2 = 0; k2 < 3; ++k2) {
      float4 z = make_float4(0.f, 0.f, 0.f, 0.f);
      *(float4*)(outz + (size_t)b * 3072 + k2 * 1024 + tid * 4) = z;
    }
    int t = b * 4 + (tid >> 6);
    int lane = tid & 63;
    const float* xr = x + (size_t)t * HD;
    int off = lane * 12;
    float4 a = *(const float4*)(xr + off);
    float4 bv = *(const float4*)(xr + off + 4);
    float4 c = *(const float4*)(xr + off + 8);
    float xv[12] = {a.x, a.y, a.z, a.w, bv.x, bv.y, bv.z, bv.w, c.x, c.y, c.z, c.w};
    bf16x4 s0, s1, s2;
#pragma unroll
    for (int j = 0; j < 4; ++j) { s0[j] = (bf16_t)xv[j]; s1[j] = (bf16_t)xv[4 + j]; s2[j] = (bf16_t)xv[8 + j]; }
    bf16_t* xo = xbf + (size_t)t * HD + off;
    *(bf16x4*)xo = s0; *(bf16x4*)(xo + 4) = s1; *(bf16x4*)(xo + 8) = s2;

    float acc[8] = {0, 0, 0, 0, 0, 0, 0, 0};
#pragma unroll
    for (int jj = 0; jj < 12; ++jj) {
      const float4* wr = (const float4*)(wg + (size_t)(off + jj) * 8);
      float4 w0 = wr[0], w1v = wr[1];
      float v = xv[jj];
      acc[0] += v * w0.x; acc[1] += v * w0.y; acc[2] += v * w0.z; acc[3] += v * w0.w;
      acc[4] += v * w1v.x; acc[5] += v * w1v.y; acc[6] += v * w1v.z; acc[7] += v * w1v.w;
    }
#pragma unroll
    for (int e = 0; e < 8; ++e) {
      float v = acc[e];
      for (int s = 1; s < 64; s <<= 1) v += __shfl_xor(v, s, 64);
      acc[e] = v;
    }
    float mx = acc[0];
#pragma unroll
    for (int e = 1; e < 8; ++e) mx = fmaxf(mx, acc[e]);
    float p[8], sum = 0.f;
#pragma unroll
    for (int e = 0; e < 8; ++e) { p[e] = __expf(acc[e] - mx); sum += p[e]; }
#pragma unroll
    for (int e = 0; e < 8; ++e) p[e] /= sum;
    if (lane == 0) {
      float4 P0 = make_float4(p[0], p[1], p[2], p[3]);
      float4 P1 = make_float4(p[4], p[5], p[6], p[7]);
      *(float4*)&probs8[t * 8] = P0;
      *(float4*)&probs8[t * 8 + 4] = P1;
      int e0 = 0;
#pragma unroll
      for (int e = 1; e < 8; ++e) if (p[e] > p[e0]) e0 = e;
      int e1 = (e0 == 0) ? 1 : 0;
#pragma unroll
      for (int e = 0; e < 8; ++e) if (e != e0 && p[e] > p[e1]) e1 = e;
      float denom = p[e0] + p[e1] + 1e-8f;
      float w0c = fminf(fmaxf(p[e0] / denom, 1e-8f), 10.f);
      float w1c = fminf(fmaxf(p[e1] / denom, 1e-8f), 10.f);
      idx2[t] = make_int2(e0, e1);
      wc2[t] = make_float2(w0c, w1c);
    }
  } else {
    // ---- weight repack: src[k][n] fp32 -> blob [kc][64n][32k] bf16 (swizzled) ----
    __shared__ bf16_t sm[32 * 68];
    int ib = b - 512;
    const float* src; bf16_t* dst; int C, KC;
    if (ib < 192) {
      int e = ib & 7, nb = ib >> 3;
      src = w1 + (size_t)e * HD * ID + nb * 64;
      dst = w1b + (size_t)((e * NB1 + nb) * KC1) * 2048;
      C = ID; KC = KC1;
    } else if (ib < 384) {
      int e = (ib - 192) & 7, nb = (ib - 192) >> 3;
      src = w3 + (size_t)e * HD * ID + nb * 64;
      dst = w3b + (size_t)((e * NB1 + nb) * KC1) * 2048;
      C = ID; KC = KC1;
    } else {
      int e = (ib - 384) & 7, nb = (ib - 384) >> 3;
      src = w2 + (size_t)e * ID * HD + nb * 64;
      dst = w2b + (size_t)((e * NB2 + nb) * KC2) * 2048;
      C = HD; KC = KC2;
    }
    int r = tid >> 3, t7 = tid & 7;
    int n = tid >> 2, pch = tid & 3;
    int cl = pch ^ ((n >> 1) & 3);
    for (int kc = 0; kc < KC; ++kc) {
      const float* sp = src + (size_t)(kc * 32 + r) * C + t7 * 8;
      float4 va = *(const float4*)sp;
      float4 vb = *(const float4*)(sp + 4);
      bf16x4 ba, bb;
      ba[0] = (bf16_t)va.x; ba[1] = (bf16_t)va.y; ba[2] = (bf16_t)va.z; ba[3] = (bf16_t)va.w;
      bb[0] = (bf16_t)vb.x; bb[1] = (bf16_t)vb.y; bb[2] = (bf16_t)vb.z; bb[3] = (bf16_t)vb.w;
      *(bf16x4*)&sm[r * 68 + t7 * 8] = ba;
      *(bf16x4*)&sm[r * 68 + t7 * 8 + 4] = bb;
      __syncthreads();
      bf16x8 o;
#pragma unroll
      for (int j = 0; j < 8; ++j) o[j] = sm[(cl * 8 + j) * 68 + n];
      *(bf16x8*)(dst + (size_t)kc * 2048 + tid * 8) = o;
      __syncthreads();
    }
  }
}

// ---------------- K2: capacity ranks + placement + aux (1 block) ----------------
__global__ void k_scan(const int2* __restrict__ idx2, const float2* __restrict__ wc2,
                       const float* __restrict__ probs8,
                       int* __restrict__ tok_of_row, float* __restrict__ wgt_of_row,
                       int2* __restrict__ cnt_start, float* __restrict__ aux_out) {
  __shared__ int2 sIdx[2048];
  __shared__ float2 sWc[2048];
  __shared__ int sTot[16];
  __shared__ int sPos[8];
  __shared__ float sImp[16][8];
  int tid = threadIdx.x;
  sIdx[tid] = idx2[tid]; sIdx[tid + 1024] = idx2[tid + 1024];
  sWc[tid] = wc2[tid];  sWc[tid + 1024] = wc2[tid + 1024];
  const float4* pp = (const float4*)probs8;
  float4 u0 = pp[tid * 4], u1 = pp[tid * 4 + 1], u2 = pp[tid * 4 + 2], u3 = pp[tid * 4 + 3];
  float im[8] = {u0.x + u2.x, u0.y + u2.y, u0.z + u2.z, u0.w + u2.w,
                 u1.x + u3.x, u1.y + u3.y, u1.z + u3.z, u1.w + u3.w};
#pragma unroll
  for (int e = 0; e < 8; ++e) {
    float v = im[e];
    for (int d = 1; d < 64; d <<= 1) v += __shfl_xor(v, d, 64);
    im[e] = v;
  }
  int w = tid >> 6, lane = tid & 63;
  if (lane == 0) {
#pragma unroll
    for (int e = 0; e < 8; ++e) sImp[w][e] = im[e];
  }
  __syncthreads();
  int s = w >> 3, e = w & 7;
  int t0 = lane * 32;
  int cnt = 0;
  for (int j = 0; j < 32; ++j) {
    int2 p = sIdx[t0 + j];
    cnt += ((s ? p.y : p.x) == e) ? 1 : 0;
  }
  int incl = cnt;
  for (int d = 1; d < 64; d <<= 1) {
    int v = __shfl_up(incl, d, 64);
    if (lane >= d) incl += v;
  }
  int excl = incl - cnt;
  if (lane == 63) sTot[w] = incl;
  __syncthreads();
  if (tid == 0) {
    int run = 0; float a = 0.f;
    for (int ee = 0; ee < 8; ++ee) {
      float impv = 0.f;
      for (int ww = 0; ww < 16; ++ww) impv += sImp[ww][ee];
      int k = min(sTot[ee], CAP) + min(sTot[8 + ee], CAP);
      sPos[ee] = run;
      cnt_start[ee] = make_int2(run, k);
      a += ((float)k / (float)TK) * (impv / (float)T_TOK);
      run += k;
    }
    a *= (float)NE;
    int dropped = TK - run;
    if (dropped > 0) a += (float)dropped / (float)T_TOK * 0.1f;
    aux_out[0] = fminf(a, 1.f) * 0.001f;
  }
  __syncthreads();
  int rank = excl;
  for (int j = 0; j < 32; ++j) {
    int t = t0 + j;
    int2 p = sIdx[t];
    int ex = s ? p.y : p.x;
    if (ex == e) {
      rank++;
      if (rank <= CAP) {
        int pos = atomicAdd(&sPos[e], 1);
        tok_of_row[pos] = t;
        float2 wv = sWc[t];
        wgt_of_row[pos] = s ? wv.y : wv.x;
      }
    }
  }
}

// ---------------- K3: grouped GEMM1 (g,u) + SiLU -> h ----------------
// grid 2304: bx = e + 8*(nb*RT + rt); tile 128m x 64n
__global__ __launch_bounds__(256, 4)
void k_gemm1(const bf16_t* __restrict__ xbf, const bf16_t* __restrict__ w1b,
             const bf16_t* __restrict__ w3b, const int* __restrict__ tok_of_row,
             const int2* __restrict__ cnt_start, bf16_t* __restrict__ h_ws) {
  int e = blockIdx.x & 7;
  int t = blockIdx.x >> 3;
  int nb = t / RT, rt = t - nb * RT;
  int2 cs = cnt_start[e];
  int nrows = cs.y - rt * 128;
  if (nrows <= 0) return;
  if (nrows > 128) nrows = 128;
  int grow0 = cs.x + rt * 128;

  __shared__ __attribute__((aligned(16))) bf16_t Abuf[128 * 32];
  __shared__ __attribute__((aligned(16))) bf16_t B1buf[64 * 32];
  __shared__ __attribute__((aligned(16))) bf16_t B3buf[64 * 32];

  int tid = threadIdx.x;
  int lane = tid & 63, wv = tid >> 6;
  int wm = wv & 1, wn = wv >> 1;
  int lr = lane & 15, q = lane >> 4;
  int rdc = (q ^ ((lane >> 1) & 3)) * 8;
  int srow = lane >> 2;
  int gch = ((lane & 3) ^ ((lane >> 3) & 3)) * 8;

  int ra = wv * 32 + srow;
  int tokA0 = tok_of_row[grow0 + min(ra, nrows - 1)];
  int tokA1 = tok_of_row[grow0 + min(ra + 16, nrows - 1)];
  const bf16_t* gA0 = xbf + (size_t)tokA0 * HD + gch;
  const bf16_t* gA1 = xbf + (size_t)tokA1 * HD + gch;
  const bf16_t* p1 = w1b + (size_t)((e * NB1 + nb) * KC1) * 2048 + tid * 8;
  const bf16_t* p3 = w3b + (size_t)((e * NB1 + nb) * KC1) * 2048 + tid * 8;
  bf16_t* lA0 = &Abuf[(wv * 32) * 32];
  bf16_t* lA1 = &Abuf[(wv * 32 + 16) * 32];
  bf16_t* lB1 = &B1buf[wv * 512];
  bf16_t* lB3 = &B3buf[wv * 512];

  floatx4 accg[4][2] = {};
  floatx4 accu[4][2] = {};

  for (int kk = 0; kk < KC1; ++kk) {
    __syncthreads();
    gld16(gA0, lA0); gld16(gA1, lA1);
    gld16(p1, lB1); gld16(p3, lB3);
    gA0 += 32; gA1 += 32; p1 += 2048; p3 += 2048;
    __syncthreads();
    bf16x8 af[4], b1f[2], b3f[2];
#pragma unroll
    for (int i = 0; i < 4; ++i) af[i] = *(const bf16x8*)&Abuf[(wm * 64 + i * 16 + lr) * 32 + rdc];
#pragma unroll
    for (int i = 0; i < 2; ++i) b1f[i] = *(const bf16x8*)&B1buf[(wn * 32 + i * 16 + lr) * 32 + rdc];
#pragma unroll
    for (int i = 0; i < 2; ++i) b3f[i] = *(const bf16x8*)&B3buf[(wn * 32 + i * 16 + lr) * 32 + rdc];
#pragma unroll
    for (int i = 0; i < 4; ++i)
#pragma unroll
      for (int jj = 0; jj < 2; ++jj) {
        accg[i][jj] = __builtin_amdgcn_mfma_f32_16x16x32_bf16(af[i], b1f[jj], accg[i][jj], 0, 0, 0);
        accu[i][jj] = __builtin_amdgcn_mfma_f32_16x16x32_bf16(af[i], b3f[jj], accu[i][jj], 0, 0, 0);
      }
  }
#pragma unroll
  for (int i = 0; i < 4; ++i)
#pragma unroll
    for (int r = 0; r < 4; ++r) {
      int rl = wm * 64 + i * 16 + q * 4 + r;
      if (rl < nrows) {
        size_t rb = (size_t)(grow0 + rl) * ID + nb * 64 + wn * 32 + lr;
#pragma unroll
        for (int jj = 0; jj < 2; ++jj) {
          float gg = accg[i][jj][r], uu = accu[i][jj][r];
          float sg = gg / (1.f + __expf(-gg));
          h_ws[rb + jj * 16] = (bf16_t)(sg * uu);
        }
      }
    }
}

// ---------------- K4: grouped GEMM2 + fused combine (atomicAdd) ----------------
// grid 1152: bx = e + 8*(nb*RT + rt); tile 128m x 64n
__global__ __launch_bounds__(256, 4)
void k_gemm2(const bf16_t* __restrict__ h_ws, const bf16_t* __restrict__ w2b,
             const int* __restrict__ tok_of_row, const float* __restrict__ wgt_of_row,
             const int2* __restrict__ cnt_start, float* __restrict__ out) {
  int e = blockIdx.x & 7;
  int t = blockIdx.x >> 3;
  int nb = t / RT, rt = t - nb * RT;
  int2 cs = cnt_start[e];
  int nrows = cs.y - rt * 128;
  if (nrows <= 0) return;
  if (nrows > 128) nrows = 128;
  int grow0 = cs.x + rt * 128;

  __shared__ __attribute__((aligned(16))) bf16_t Abuf[128 * 32];
  __shared__ __attribute__((aligned(16))) bf16_t Bbuf[64 * 32];

  int tid = threadIdx.x;
  int lane = tid & 63, wv = tid >> 6;
  int wm = wv & 1, wn = wv >> 1;
  int lr = lane & 15, q = lane >> 4;
  int rdc = (q ^ ((lane >> 1) & 3)) * 8;
  int srow = lane >> 2;
  int gch = ((lane & 3) ^ ((lane >> 3) & 3)) * 8;

  int ra = wv * 32 + srow;
  const bf16_t* gA0 = h_ws + (size_t)(grow0 + min(ra, nrows - 1)) * ID + gch;
  const bf16_t* gA1 = h_ws + (size_t)(grow0 + min(ra + 16, nrows - 1)) * ID + gch;
  const bf16_t* pB = w2b + (size_t)((e * NB2 + nb) * KC2) * 2048 + tid * 8;
  bf16_t* lA0 = &Abuf[(wv * 32) * 32];
  bf16_t* lA1 = &Abuf[(wv * 32 + 16) * 32];
  bf16_t* lB = &Bbuf[wv * 512];

  floatx4 acc[4][2] = {};

  for (int kk = 0; kk < KC2; ++kk) {
    __syncthreads();
    gld16(gA0, lA0); gld16(gA1, lA1);
    gld16(pB, lB);
    gA0 += 32; gA1 += 32; pB += 2048;
    __syncthreads();
    bf16x8 af[4], bfr[2];
#pragma unroll
    for (int i = 0; i < 4; ++i) af[i] = *(const bf16x8*)&Abuf[(wm * 64 + i * 16 + lr) * 32 + rdc];
#pragma unroll
    for (int i = 0; i < 2; ++i) bfr[i] = *(const bf16x8*)&Bbuf[(wn * 32 + i * 16 + lr) * 32 + rdc];
#pragma unroll
    for (int i = 0; i < 4; ++i)
#pragma unroll
      for (int jj = 0; jj < 2; ++jj)
        acc[i][jj] = __builtin_amdgcn_mfma_f32_16x16x32_bf16(af[i], bfr[jj], acc[i][jj], 0, 0, 0);
  }
#pragma unroll
  for (int i = 0; i < 4; ++i)
#pragma unroll
    for (int r = 0; r < 4; ++r) {
      int rl = wm * 64 + i * 16 + q * 4 + r;
      if (rl < nrows) {
        int grow = grow0 + rl;
        int tok = tok_of_row[grow];
        float wgt = wgt_of_row[grow];
        size_t ob = (size_t)tok * HD + nb * 64 + wn * 32 + lr;
#pragma unroll
        for (int jj = 0; jj < 2; ++jj)
          atomicAdd(&out[ob + jj * 16], wgt * acc[i][jj][r]);
      }
    }
}

extern "C" void kernel_launch(void* const* d_in, const int* in_sizes, int n_in,
                              void* d_out, int out_size, void* d_ws, size_t ws_size,
                              hipStream_t stream) {
  const float* x  = (const float*)d_in[0];
  const float* wg = (const float*)d_in[1];
  const float* w1 = (const float*)d_in[2];
  const float* w3 = (const float*)d_in[3];
  const float* w2 = (const float*)d_in[4];
  float* out = (float*)d_out;

  char* ws = (char*)d_ws;
  bf16_t* xbf  = (bf16_t*)(ws + 0);          //  3,145,728
  bf16_t* w1b  = (bf16_t*)(ws + 3145728);    // 18,874,368
  bf16_t* w3b  = (bf16_t*)(ws + 22020096);   // 18,874,368
  bf16_t* w2b  = (bf16_t*)(ws + 40894464);   // 18,874,368
  bf16_t* h_ws = (bf16_t*)(ws + 59768832);   // 12,582,912
  float*  probs8     = (float*)(ws + 72351744);   // 65,536
  int2*   idx2       = (int2*)(ws + 72417280);
  float2* wc2        = (float2*)(ws + 72433664);
  int*    tok_of_row = (int*)(ws + 72450048);
  float*  wgt_of_row = (float*)(ws + 72466432);
  int2*   cnt_start  = (int2*)(ws + 72482816);

  float* aux_out = out + (size_t)T_TOK * HD;

  k_prep<<<992, 256, 0, stream>>>(x, wg, w1, w3, w2, xbf, w1b, w3b, w2b,
                                  idx2, wc2, probs8, out);
  k_scan<<<1, 1024, 0, stream>>>(idx2, wc2, probs8, tok_of_row, wgt_of_row,
                                 cnt_start, aux_out);
  k_gemm1<<<8 * NB1 * RT, 256, 0, stream>>>(xbf, w1b, w3b, tok_of_row,
                                            cnt_start, h_ws);
  k_gemm2<<<8 * NB2 * RT, 256, 0, stream>>>(h_ws, w2b, tok_of_row, wgt_of_row,
                                            cnt_start, out);
}

// Round 5
// 262.167 us; speedup vs baseline: 1.8418x; 1.0596x over previous
//
#include <hip/hip_runtime.h>
#include <math.h>

#define T_TOK 2048
#define HD 768
#define ID 1536
#define NE 8
#define CAP 768
#define TK 4096
#define RT 12      // max 128-row tiles per expert (2*CAP/128)
#define NB1 24     // ID/64 col-strips for gemm1
#define KC1 24     // HD/32 K-steps for gemm1
#define NB2 12     // HD/64 col-strips for gemm2
#define KC2 48     // ID/32 K-steps for gemm2

typedef __bf16 bf16_t;
typedef __bf16 bf16x8 __attribute__((ext_vector_type(8)));
typedef __bf16 bf16x4 __attribute__((ext_vector_type(4)));
typedef float floatx4 __attribute__((ext_vector_type(4)));

__device__ __forceinline__ void gld16(const bf16_t* g, bf16_t* l) {
  __builtin_amdgcn_global_load_lds(
      (__attribute__((address_space(1))) void*)(g),
      (__attribute__((address_space(3))) void*)(l),
      16, 0, 0);
}

// ---------------- K1: fused routing + out-zero + weight repack ----------------
// blocks [0,512): routing (4 tokens/block, wave per token) + zero out slice
// blocks [512,2240): barrier-free repack fp32 -> pre-swizzled bf16 blobs.
//   Thread (n=tid>>2, p=tid&3) reads its fragment octet c8 = p^((n>>1)&3)
//   directly from global (8 dword loads = 4x64B full segments per wave instr)
//   and stores bf16x8 sequentially. No LDS, no barriers.
__global__ void k_prep(const float* __restrict__ x, const float* __restrict__ wg,
                       const float* __restrict__ w1, const float* __restrict__ w3,
                       const float* __restrict__ w2,
                       bf16_t* __restrict__ xbf, bf16_t* __restrict__ w1b,
                       bf16_t* __restrict__ w3b, bf16_t* __restrict__ w2b,
                       int2* __restrict__ idx2, float2* __restrict__ wc2,
                       float* __restrict__ probs8, float* __restrict__ outz) {
  int b = blockIdx.x;
  int tid = threadIdx.x;
  if (b < 512) {
#pragma unroll
    for (int k2 = 0; k2 < 3; ++k2) {
      float4 z = make_float4(0.f, 0.f, 0.f, 0.f);
      *(float4*)(outz + (size_t)b * 3072 + k2 * 1024 + tid * 4) = z;
    }
    int t = b * 4 + (tid >> 6);
    int lane = tid & 63;
    const float* xr = x + (size_t)t * HD;
    int off = lane * 12;
    float4 a = *(const float4*)(xr + off);
    float4 bv = *(const float4*)(xr + off + 4);
    float4 c = *(const float4*)(xr + off + 8);
    float xv[12] = {a.x, a.y, a.z, a.w, bv.x, bv.y, bv.z, bv.w, c.x, c.y, c.z, c.w};
    bf16x4 s0, s1, s2;
#pragma unroll
    for (int j = 0; j < 4; ++j) { s0[j] = (bf16_t)xv[j]; s1[j] = (bf16_t)xv[4 + j]; s2[j] = (bf16_t)xv[8 + j]; }
    bf16_t* xo = xbf + (size_t)t * HD + off;
    *(bf16x4*)xo = s0; *(bf16x4*)(xo + 4) = s1; *(bf16x4*)(xo + 8) = s2;

    float acc[8] = {0, 0, 0, 0, 0, 0, 0, 0};
#pragma unroll
    for (int jj = 0; jj < 12; ++jj) {
      const float4* wr = (const float4*)(wg + (size_t)(off + jj) * 8);
      float4 w0 = wr[0], w1v = wr[1];
      float v = xv[jj];
      acc[0] += v * w0.x; acc[1] += v * w0.y; acc[2] += v * w0.z; acc[3] += v * w0.w;
      acc[4] += v * w1v.x; acc[5] += v * w1v.y; acc[6] += v * w1v.z; acc[7] += v * w1v.w;
    }
#pragma unroll
    for (int e = 0; e < 8; ++e) {
      float v = acc[e];
      for (int s = 1; s < 64; s <<= 1) v += __shfl_xor(v, s, 64);
      acc[e] = v;
    }
    float mx = acc[0];
#pragma unroll
    for (int e = 1; e < 8; ++e) mx = fmaxf(mx, acc[e]);
    float p[8], sum = 0.f;
#pragma unroll
    for (int e = 0; e < 8; ++e) { p[e] = __expf(acc[e] - mx); sum += p[e]; }
#pragma unroll
    for (int e = 0; e < 8; ++e) p[e] /= sum;
    if (lane == 0) {
      float4 P0 = make_float4(p[0], p[1], p[2], p[3]);
      float4 P1 = make_float4(p[4], p[5], p[6], p[7]);
      *(float4*)&probs8[t * 8] = P0;
      *(float4*)&probs8[t * 8 + 4] = P1;
      int e0 = 0;
#pragma unroll
      for (int e = 1; e < 8; ++e) if (p[e] > p[e0]) e0 = e;
      int e1 = (e0 == 0) ? 1 : 0;
#pragma unroll
      for (int e = 0; e < 8; ++e) if (e != e0 && p[e] > p[e1]) e1 = e;
      float denom = p[e0] + p[e1] + 1e-8f;
      float w0c = fminf(fmaxf(p[e0] / denom, 1e-8f), 10.f);
      float w1c = fminf(fmaxf(p[e1] / denom, 1e-8f), 10.f);
      idx2[t] = make_int2(e0, e1);
      wc2[t] = make_float2(w0c, w1c);
    }
  } else {
    int rb = b - 512;  // [0,1728): 576 w1 + 576 w3 + 576 w2; 8 kc-tiles/block
    const float* src; bf16_t* dst; int C; int kc0;
    if (rb < 1152) {
      int m = rb >= 576;
      int r3 = m ? rb - 576 : rb;
      int pan = r3 / 3;                 // (e,nb) panel, 192 of them
      kc0 = (r3 - pan * 3) * 8;
      int e = pan & 7, nb = pan >> 3;   // nb in [0,24)
      src = (m ? w3 : w1) + (size_t)e * HD * ID + nb * 64;
      dst = (m ? w3b : w1b) + (size_t)(e * NB1 + nb) * (KC1 * 2048);
      C = ID;
    } else {
      int q = rb - 1152;
      int pan = q / 6;                  // 96 panels
      kc0 = (q - pan * 6) * 8;
      int e = pan & 7, nb = pan >> 3;   // nb in [0,12)
      src = w2 + (size_t)e * ID * HD + nb * 64;
      dst = w2b + (size_t)(e * NB2 + nb) * (KC2 * 2048);
      C = HD;
    }
    int n = tid >> 2, p4 = tid & 3;
    int c8 = p4 ^ ((n >> 1) & 3);
    const float* sp0 = src + n + (size_t)(kc0 * 32 + c8 * 8) * C;
    bf16_t* dp = dst + (size_t)kc0 * 2048 + tid * 8;
#pragma unroll 2
    for (int t = 0; t < 8; ++t) {
      const float* sp = sp0 + (size_t)t * 32 * C;
      float v[8];
#pragma unroll
      for (int j = 0; j < 8; ++j) v[j] = sp[(size_t)j * C];
      bf16x8 o;
#pragma unroll
      for (int j = 0; j < 8; ++j) o[j] = (bf16_t)v[j];
      *(bf16x8*)(dp + t * 2048) = o;
    }
  }
}

// ---------------- K2: capacity ranks + placement + aux (1 block) ----------------
__global__ void k_scan(const int2* __restrict__ idx2, const float2* __restrict__ wc2,
                       const float* __restrict__ probs8,
                       int* __restrict__ tok_of_row, float* __restrict__ wgt_of_row,
                       int2* __restrict__ cnt_start, float* __restrict__ aux_out) {
  __shared__ int2 sIdx[2048];
  __shared__ float2 sWc[2048];
  __shared__ int sTot[16];
  __shared__ int sPos[8];
  __shared__ float sImp[16][8];
  int tid = threadIdx.x;
  sIdx[tid] = idx2[tid]; sIdx[tid + 1024] = idx2[tid + 1024];
  sWc[tid] = wc2[tid];  sWc[tid + 1024] = wc2[tid + 1024];
  const float4* pp = (const float4*)probs8;
  float4 u0 = pp[tid * 4], u1 = pp[tid * 4 + 1], u2 = pp[tid * 4 + 2], u3 = pp[tid * 4 + 3];
  float im[8] = {u0.x + u2.x, u0.y + u2.y, u0.z + u2.z, u0.w + u2.w,
                 u1.x + u3.x, u1.y + u3.y, u1.z + u3.z, u1.w + u3.w};
#pragma unroll
  for (int e = 0; e < 8; ++e) {
    float v = im[e];
    for (int d = 1; d < 64; d <<= 1) v += __shfl_xor(v, d, 64);
    im[e] = v;
  }
  int w = tid >> 6, lane = tid & 63;
  if (lane == 0) {
#pragma unroll
    for (int e = 0; e < 8; ++e) sImp[w][e] = im[e];
  }
  __syncthreads();
  int s = w >> 3, e = w & 7;
  int t0 = lane * 32;
  int cnt = 0;
  for (int j = 0; j < 32; ++j) {
    int2 p = sIdx[t0 + j];
    cnt += ((s ? p.y : p.x) == e) ? 1 : 0;
  }
  int incl = cnt;
  for (int d = 1; d < 64; d <<= 1) {
    int v = __shfl_up(incl, d, 64);
    if (lane >= d) incl += v;
  }
  int excl = incl - cnt;
  if (lane == 63) sTot[w] = incl;
  __syncthreads();
  if (tid == 0) {
    int run = 0; float a = 0.f;
    for (int ee = 0; ee < 8; ++ee) {
      float impv = 0.f;
      for (int ww = 0; ww < 16; ++ww) impv += sImp[ww][ee];
      int k = min(sTot[ee], CAP) + min(sTot[8 + ee], CAP);
      sPos[ee] = run;
      cnt_start[ee] = make_int2(run, k);
      a += ((float)k / (float)TK) * (impv / (float)T_TOK);
      run += k;
    }
    a *= (float)NE;
    int dropped = TK - run;
    if (dropped > 0) a += (float)dropped / (float)T_TOK * 0.1f;
    aux_out[0] = fminf(a, 1.f) * 0.001f;
  }
  __syncthreads();
  int rank = excl;
  for (int j = 0; j < 32; ++j) {
    int t = t0 + j;
    int2 p = sIdx[t];
    int ex = s ? p.y : p.x;
    if (ex == e) {
      rank++;
      if (rank <= CAP) {
        int pos = atomicAdd(&sPos[e], 1);
        tok_of_row[pos] = t;
        float2 wv = sWc[t];
        wgt_of_row[pos] = s ? wv.y : wv.x;
      }
    }
  }
}

// ---------------- K3: grouped GEMM1 (g,u) + SiLU -> h ----------------
// grid 2304: bx = e + 8*(nb*RT + rt); tile 128m x 64n
__global__ __launch_bounds__(256, 4)
void k_gemm1(const bf16_t* __restrict__ xbf, const bf16_t* __restrict__ w1b,
             const bf16_t* __restrict__ w3b, const int* __restrict__ tok_of_row,
             const int2* __restrict__ cnt_start, bf16_t* __restrict__ h_ws) {
  int e = blockIdx.x & 7;
  int t = blockIdx.x >> 3;
  int nb = t / RT, rt = t - nb * RT;
  int2 cs = cnt_start[e];
  int nrows = cs.y - rt * 128;
  if (nrows <= 0) return;
  if (nrows > 128) nrows = 128;
  int grow0 = cs.x + rt * 128;

  __shared__ __attribute__((aligned(16))) bf16_t Abuf[128 * 32];
  __shared__ __attribute__((aligned(16))) bf16_t B1buf[64 * 32];
  __shared__ __attribute__((aligned(16))) bf16_t B3buf[64 * 32];

  int tid = threadIdx.x;
  int lane = tid & 63, wv = tid >> 6;
  int wm = wv & 1, wn = wv >> 1;
  int lr = lane & 15, q = lane >> 4;
  int rdc = (q ^ ((lane >> 1) & 3)) * 8;
  int srow = lane >> 2;
  int gch = ((lane & 3) ^ ((lane >> 3) & 3)) * 8;

  int ra = wv * 32 + srow;
  int tokA0 = tok_of_row[grow0 + min(ra, nrows - 1)];
  int tokA1 = tok_of_row[grow0 + min(ra + 16, nrows - 1)];
  const bf16_t* gA0 = xbf + (size_t)tokA0 * HD + gch;
  const bf16_t* gA1 = xbf + (size_t)tokA1 * HD + gch;
  const bf16_t* p1 = w1b + (size_t)((e * NB1 + nb) * KC1) * 2048 + tid * 8;
  const bf16_t* p3 = w3b + (size_t)((e * NB1 + nb) * KC1) * 2048 + tid * 8;
  bf16_t* lA0 = &Abuf[(wv * 32) * 32];
  bf16_t* lA1 = &Abuf[(wv * 32 + 16) * 32];
  bf16_t* lB1 = &B1buf[wv * 512];
  bf16_t* lB3 = &B3buf[wv * 512];

  floatx4 accg[4][2] = {};
  floatx4 accu[4][2] = {};

  for (int kk = 0; kk < KC1; ++kk) {
    __syncthreads();
    gld16(gA0, lA0); gld16(gA1, lA1);
    gld16(p1, lB1); gld16(p3, lB3);
    gA0 += 32; gA1 += 32; p1 += 2048; p3 += 2048;
    __syncthreads();
    bf16x8 af[4], b1f[2], b3f[2];
#pragma unroll
    for (int i = 0; i < 4; ++i) af[i] = *(const bf16x8*)&Abuf[(wm * 64 + i * 16 + lr) * 32 + rdc];
#pragma unroll
    for (int i = 0; i < 2; ++i) b1f[i] = *(const bf16x8*)&B1buf[(wn * 32 + i * 16 + lr) * 32 + rdc];
#pragma unroll
    for (int i = 0; i < 2; ++i) b3f[i] = *(const bf16x8*)&B3buf[(wn * 32 + i * 16 + lr) * 32 + rdc];
#pragma unroll
    for (int i = 0; i < 4; ++i)
#pragma unroll
      for (int jj = 0; jj < 2; ++jj) {
        accg[i][jj] = __builtin_amdgcn_mfma_f32_16x16x32_bf16(af[i], b1f[jj], accg[i][jj], 0, 0, 0);
        accu[i][jj] = __builtin_amdgcn_mfma_f32_16x16x32_bf16(af[i], b3f[jj], accu[i][jj], 0, 0, 0);
      }
  }
#pragma unroll
  for (int i = 0; i < 4; ++i)
#pragma unroll
    for (int r = 0; r < 4; ++r) {
      int rl = wm * 64 + i * 16 + q * 4 + r;
      if (rl < nrows) {
        size_t rb = (size_t)(grow0 + rl) * ID + nb * 64 + wn * 32 + lr;
#pragma unroll
        for (int jj = 0; jj < 2; ++jj) {
          float gg = accg[i][jj][r], uu = accu[i][jj][r];
          float sg = gg / (1.f + __expf(-gg));
          h_ws[rb + jj * 16] = (bf16_t)(sg * uu);
        }
      }
    }
}

// ---------------- K4: grouped GEMM2 + fused combine (atomicAdd) ----------------
// grid 1152: bx = e + 8*(nb*RT + rt); tile 128m x 64n
__global__ __launch_bounds__(256, 4)
void k_gemm2(const bf16_t* __restrict__ h_ws, const bf16_t* __restrict__ w2b,
             const int* __restrict__ tok_of_row, const float* __restrict__ wgt_of_row,
             const int2* __restrict__ cnt_start, float* __restrict__ out) {
  int e = blockIdx.x & 7;
  int t = blockIdx.x >> 3;
  int nb = t / RT, rt = t - nb * RT;
  int2 cs = cnt_start[e];
  int nrows = cs.y - rt * 128;
  if (nrows <= 0) return;
  if (nrows > 128) nrows = 128;
  int grow0 = cs.x + rt * 128;

  __shared__ __attribute__((aligned(16))) bf16_t Abuf[128 * 32];
  __shared__ __attribute__((aligned(16))) bf16_t Bbuf[64 * 32];

  int tid = threadIdx.x;
  int lane = tid & 63, wv = tid >> 6;
  int wm = wv & 1, wn = wv >> 1;
  int lr = lane & 15, q = lane >> 4;
  int rdc = (q ^ ((lane >> 1) & 3)) * 8;
  int srow = lane >> 2;
  int gch = ((lane & 3) ^ ((lane >> 3) & 3)) * 8;

  int ra = wv * 32 + srow;
  const bf16_t* gA0 = h_ws + (size_t)(grow0 + min(ra, nrows - 1)) * ID + gch;
  const bf16_t* gA1 = h_ws + (size_t)(grow0 + min(ra + 16, nrows - 1)) * ID + gch;
  const bf16_t* pB = w2b + (size_t)((e * NB2 + nb) * KC2) * 2048 + tid * 8;
  bf16_t* lA0 = &Abuf[(wv * 32) * 32];
  bf16_t* lA1 = &Abuf[(wv * 32 + 16) * 32];
  bf16_t* lB = &Bbuf[wv * 512];

  floatx4 acc[4][2] = {};

  for (int kk = 0; kk < KC2; ++kk) {
    __syncthreads();
    gld16(gA0, lA0); gld16(gA1, lA1);
    gld16(pB, lB);
    gA0 += 32; gA1 += 32; pB += 2048;
    __syncthreads();
    bf16x8 af[4], bfr[2];
#pragma unroll
    for (int i = 0; i < 4; ++i) af[i] = *(const bf16x8*)&Abuf[(wm * 64 + i * 16 + lr) * 32 + rdc];
#pragma unroll
    for (int i = 0; i < 2; ++i) bfr[i] = *(const bf16x8*)&Bbuf[(wn * 32 + i * 16 + lr) * 32 + rdc];
#pragma unroll
    for (int i = 0; i < 4; ++i)
#pragma unroll
      for (int jj = 0; jj < 2; ++jj)
        acc[i][jj] = __builtin_amdgcn_mfma_f32_16x16x32_bf16(af[i], bfr[jj], acc[i][jj], 0, 0, 0);
  }
#pragma unroll
  for (int i = 0; i < 4; ++i)
#pragma unroll
    for (int r = 0; r < 4; ++r) {
      int rl = wm * 64 + i * 16 + q * 4 + r;
      if (rl < nrows) {
        int grow = grow0 + rl;
        int tok = tok_of_row[grow];
        float wgt = wgt_of_row[grow];
        size_t ob = (size_t)tok * HD + nb * 64 + wn * 32 + lr;
#pragma unroll
        for (int jj = 0; jj < 2; ++jj)
          atomicAdd(&out[ob + jj * 16], wgt * acc[i][jj][r]);
      }
    }
}

extern "C" void kernel_launch(void* const* d_in, const int* in_sizes, int n_in,
                              void* d_out, int out_size, void* d_ws, size_t ws_size,
                              hipStream_t stream) {
  const float* x  = (const float*)d_in[0];
  const float* wg = (const float*)d_in[1];
  const float* w1 = (const float*)d_in[2];
  const float* w3 = (const float*)d_in[3];
  const float* w2 = (const float*)d_in[4];
  float* out = (float*)d_out;

  char* ws = (char*)d_ws;
  bf16_t* xbf  = (bf16_t*)(ws + 0);          //  3,145,728
  bf16_t* w1b  = (bf16_t*)(ws + 3145728);    // 18,874,368
  bf16_t* w3b  = (bf16_t*)(ws + 22020096);   // 18,874,368
  bf16_t* w2b  = (bf16_t*)(ws + 40894464);   // 18,874,368
  bf16_t* h_ws = (bf16_t*)(ws + 59768832);   // 12,582,912
  float*  probs8     = (float*)(ws + 72351744);   // 65,536
  int2*   idx2       = (int2*)(ws + 72417280);
  float2* wc2        = (float2*)(ws + 72433664);
  int*    tok_of_row = (int*)(ws + 72450048);
  float*  wgt_of_row = (float*)(ws + 72466432);
  int2*   cnt_start  = (int2*)(ws + 72482816);

  float* aux_out = out + (size_t)T_TOK * HD;

  k_prep<<<2240, 256, 0, stream>>>(x, wg, w1, w3, w2, xbf, w1b, w3b, w2b,
                                   idx2, wc2, probs8, out);
  k_scan<<<1, 1024, 0, stream>>>(idx2, wc2, probs8, tok_of_row, wgt_of_row,
                                 cnt_start, aux_out);
  k_gemm1<<<8 * NB1 * RT, 256, 0, stream>>>(xbf, w1b, w3b, tok_of_row,
                                            cnt_start, h_ws);
  k_gemm2<<<8 * NB2 * RT, 256, 0, stream>>>(h_ws, w2b, tok_of_row, wgt_of_row,
                                            cnt_start, out);
}